// Round 2
// baseline (1186.877 us; speedup 1.0000x reference)
//
#include <hip/hip_runtime.h>
#include <hip/hip_bf16.h>

typedef __bf16 bf16;
typedef __attribute__((ext_vector_type(8))) __bf16 bf16x8;
typedef __attribute__((ext_vector_type(4))) float floatx4;

__device__ __forceinline__ unsigned short f2b(float f) {
  union { bf16 h; unsigned short u; } v; v.h = (bf16)f; return v.u;
}
__device__ __forceinline__ float b2f(unsigned short u) {
  union { unsigned int i; float f; } v; v.i = ((unsigned int)u) << 16; return v.f;
}

__device__ __forceinline__ void async_copy16(const void* g, void* l) {
  __builtin_amdgcn_global_load_lds((__attribute__((address_space(1))) void*)(g),
                                   (__attribute__((address_space(3))) void*)(l),
                                   16, 0, 0);
}

__device__ __forceinline__ float warp_sum(float v) {
  #pragma unroll
  for (int off = 32; off > 0; off >>= 1) v += __shfl_xor(v, off, 64);
  return v;
}
__device__ __forceinline__ float warp_max(float v) {
  #pragma unroll
  for (int off = 32; off > 0; off >>= 1) v = fmaxf(v, __shfl_xor(v, off, 64));
  return v;
}

// dtype-generic 4-element load
__device__ __forceinline__ void load4(const float* p, float* v) {
  float4 u = *(const float4*)p;
  v[0] = u.x; v[1] = u.y; v[2] = u.z; v[3] = u.w;
}
__device__ __forceinline__ void load4(const bf16* p, float* v) {
  ushort4 u = *(const ushort4*)p;
  v[0] = b2f(u.x); v[1] = b2f(u.y); v[2] = b2f(u.z); v[3] = b2f(u.w);
}

// ---------------- weight absmean (per-tensor, fp32 input) ----------------
__global__ __launch_bounds__(256) void absmean_partial(const float* __restrict__ w, int n,
                                                       float* __restrict__ partial) {
  const int tid = threadIdx.x;
  const int lane = tid & 63, wave = tid >> 6;
  float s = 0.f;
  for (size_t i = ((size_t)blockIdx.x * 256 + tid) * 4; i < (size_t)n;
       i += (size_t)256 * 256 * 4) {
    float4 u = *(const float4*)(w + i);
    s += fabsf(u.x) + fabsf(u.y) + fabsf(u.z) + fabsf(u.w);
  }
  __shared__ float red[4];
  s = warp_sum(s);
  if (lane == 0) red[wave] = s;
  __syncthreads();
  if (tid == 0) partial[blockIdx.x] = red[0] + red[1] + red[2] + red[3];
}

// scales: [0]=s_w1 (quant), [1]=dq_w1, [2]=s_w2, [3]=dq_w2
__global__ __launch_bounds__(256) void finalize_scales(const float* __restrict__ p1,
                                                       const float* __restrict__ p2,
                                                       float inv_n1, float inv_n2,
                                                       float* __restrict__ scales) {
  const int tid = threadIdx.x;
  const int lane = tid & 63, wave = tid >> 6;
  float a = p1[tid], b = p2[tid];
  a = warp_sum(a); b = warp_sum(b);
  __shared__ float red[8];
  if (lane == 0) { red[wave] = a; red[4 + wave] = b; }
  __syncthreads();
  if (tid == 0) {
    float m1 = fmaxf((red[0] + red[1] + red[2] + red[3]) * inv_n1, 1e-5f);
    float m2 = fmaxf((red[4] + red[5] + red[6] + red[7]) * inv_n2, 1e-5f);
    scales[0] = 1.0f / m1; scales[1] = m1;
    scales[2] = 1.0f / m2; scales[3] = m2;
  }
}

// ternarize fp32 weights -> bf16 {-1,0,1}
__global__ __launch_bounds__(256) void quant_w(const float* __restrict__ w,
                                               bf16* __restrict__ wq,
                                               const float* __restrict__ sptr, int n) {
  const int i4 = (blockIdx.x * 256 + threadIdx.x) * 4;
  if (i4 >= n) return;
  const float s = *sptr;
  float4 u = *(const float4*)(w + i4);
  ushort4 o;
  o.x = f2b(fminf(fmaxf(rintf(u.x * s), -1.f), 1.f));
  o.y = f2b(fminf(fmaxf(rintf(u.y * s), -1.f), 1.f));
  o.z = f2b(fminf(fmaxf(rintf(u.z * s), -1.f), 1.f));
  o.w = f2b(fminf(fmaxf(rintf(u.w * s), -1.f), 1.f));
  *(ushort4*)(wq + i4) = o;
}

// ---------------- layernorm + per-row int8 fake quant ----------------
// one block (256 thr) per row. q may alias x row storage (in-place): all reads of
// the row complete before the first __syncthreads; writes happen after the second.
// px = input row pitch (XT elements), pq = output row pitch (bf16 elements).
template <int D, typename XT>
__global__ __launch_bounds__(256) void ln_quant_kernel(const XT* __restrict__ x,
                                                       const float* __restrict__ gam,
                                                       const float* __restrict__ bet,
                                                       bf16* __restrict__ q,
                                                       float* __restrict__ rdq,
                                                       int px, int pq) {
  constexpr int NC = D / 1024;  // 4-element chunks per thread
  const int tid = threadIdx.x;
  const int lane = tid & 63, wave = tid >> 6;
  const size_t xbase = (size_t)blockIdx.x * px;
  const size_t qbase = (size_t)blockIdx.x * pq;
  float y[NC * 4];
  float s = 0.f, ss = 0.f;
  #pragma unroll
  for (int c = 0; c < NC; ++c) {
    const int idx = (c * 256 + tid) * 4;
    float v[4];
    load4(x + xbase + idx, v);
    #pragma unroll
    for (int j = 0; j < 4; ++j) { y[c * 4 + j] = v[j]; s += v[j]; ss += v[j] * v[j]; }
  }
  __shared__ float red[12];
  float sw = warp_sum(s), qw = warp_sum(ss);
  if (lane == 0) { red[wave] = sw; red[4 + wave] = qw; }
  __syncthreads();
  const float inv_d = 1.0f / (float)D;
  const float mu = (red[0] + red[1] + red[2] + red[3]) * inv_d;
  const float var = (red[4] + red[5] + red[6] + red[7]) * inv_d - mu * mu;
  const float rstd = rsqrtf(var + 1e-5f);
  float amax = 0.f;
  #pragma unroll
  for (int c = 0; c < NC; ++c) {
    const int idx = (c * 256 + tid) * 4;
    float4 gv = *(const float4*)(gam + idx);
    float4 bv = *(const float4*)(bet + idx);
    float gg[4] = {gv.x, gv.y, gv.z, gv.w};
    float bb[4] = {bv.x, bv.y, bv.z, bv.w};
    #pragma unroll
    for (int j = 0; j < 4; ++j) {
      float yy = (y[c * 4 + j] - mu) * rstd * gg[j] + bb[j];
      y[c * 4 + j] = yy;
      amax = fmaxf(amax, fabsf(yy));
    }
  }
  float wm = warp_max(amax);
  if (lane == 0) red[8 + wave] = wm;
  __syncthreads();
  const float am = fmaxf(fmaxf(fmaxf(red[8], red[9]), fmaxf(red[10], red[11])), 1e-5f);
  const float sc = 127.0f / am;
  #pragma unroll
  for (int c = 0; c < NC; ++c) {
    const int idx = (c * 256 + tid) * 4;
    ushort4 o;
    o.x = f2b(fminf(fmaxf(rintf(y[c * 4 + 0] * sc), -128.f), 127.f));
    o.y = f2b(fminf(fmaxf(rintf(y[c * 4 + 1] * sc), -128.f), 127.f));
    o.z = f2b(fminf(fmaxf(rintf(y[c * 4 + 2] * sc), -128.f), 127.f));
    o.w = f2b(fminf(fmaxf(rintf(y[c * 4 + 3] * sc), -128.f), 127.f));
    *(ushort4*)(q + qbase + idx) = o;
  }
  if (tid == 0) rdq[blockIdx.x] = am * (1.0f / 127.0f);
}

// ---------------- quantized GEMM: C[M,N] = A[M,K] * B[N,K]^T (m97 structure) ------------
// A row pitch = lda (bf16 elems), B row pitch = K, C row pitch = ldc (CT elems).
template <bool GELU, typename CT>
__global__ __launch_bounds__(256) void gemm_q(const bf16* __restrict__ A,
                                              const bf16* __restrict__ B,
                                              CT* __restrict__ C,
                                              const float* __restrict__ rdq,
                                              const float* __restrict__ wdq_ptr,
                                              const float* __restrict__ bias,
                                              int N, int K, int lda, int ldc) {
  __shared__ bf16 ldsA[128 * 32];
  __shared__ bf16 ldsB[128 * 32];
  const int tid = threadIdx.x;
  const int wave = tid >> 6, lane = tid & 63;
  const int quad = lane >> 4, l16 = lane & 15;
  const int nb = N >> 7;
  const int bm = (int)blockIdx.x / nb;
  const int bn = (int)blockIdx.x % nb;
  const int wm = wave & 1, wn = wave >> 1;

  // staging: 512 16B-chunks per operand tile; chunk = row*4 + colquarter
  const int ch0 = wave * 128 + lane;
  const int ch1 = ch0 + 64;
  const bf16* a0 = A + (size_t)(bm * 128 + (ch0 >> 2)) * lda + (ch0 & 3) * 8;
  const bf16* a1 = A + (size_t)(bm * 128 + (ch1 >> 2)) * lda + (ch1 & 3) * 8;
  const bf16* b0 = B + (size_t)(bn * 128 + (ch0 >> 2)) * K + (ch0 & 3) * 8;
  const bf16* b1 = B + (size_t)(bn * 128 + (ch1 >> 2)) * K + (ch1 & 3) * 8;
  bf16* la0 = &ldsA[(wave * 128) * 8];       // hw adds lane*16B
  bf16* la1 = &ldsA[(wave * 128 + 64) * 8];
  bf16* lb0 = &ldsB[(wave * 128) * 8];
  bf16* lb1 = &ldsB[(wave * 128 + 64) * 8];

  floatx4 acc[4][4];
  #pragma unroll
  for (int i = 0; i < 4; ++i)
    #pragma unroll
    for (int j = 0; j < 4; ++j) acc[i][j] = (floatx4){0.f, 0.f, 0.f, 0.f};

  const float wdq = *wdq_ptr;

  for (int k0 = 0; k0 < K; k0 += 32) {
    __syncthreads();
    async_copy16(a0 + k0, la0);
    async_copy16(a1 + k0, la1);
    async_copy16(b0 + k0, lb0);
    async_copy16(b1 + k0, lb1);
    __syncthreads();  // s_waitcnt vmcnt(0) drains global_load_lds before barrier
    bf16x8 af[4], bfr[4];
    #pragma unroll
    for (int mi = 0; mi < 4; ++mi) {
      int r = wm * 64 + mi * 16 + l16;
      af[mi] = *(const bf16x8*)&ldsA[r * 32 + quad * 8];
    }
    #pragma unroll
    for (int ni = 0; ni < 4; ++ni) {
      int r = wn * 64 + ni * 16 + l16;
      bfr[ni] = *(const bf16x8*)&ldsB[r * 32 + quad * 8];
    }
    #pragma unroll
    for (int mi = 0; mi < 4; ++mi)
      #pragma unroll
      for (int ni = 0; ni < 4; ++ni)
        acc[mi][ni] =
            __builtin_amdgcn_mfma_f32_16x16x32_bf16(af[mi], bfr[ni], acc[mi][ni], 0, 0, 0);
  }

  // epilogue: C/D layout col=lane&15, row=quad*4+reg (verified m89)
  #pragma unroll
  for (int mi = 0; mi < 4; ++mi) {
    const int rowb = bm * 128 + wm * 64 + mi * 16 + quad * 4;
    const floatx4 rd = *(const floatx4*)&rdq[rowb];
    #pragma unroll
    for (int ni = 0; ni < 4; ++ni) {
      const int col = bn * 128 + wn * 64 + ni * 16 + l16;
      const float bv = bias[col];
      #pragma unroll
      for (int r2 = 0; r2 < 4; ++r2) {
        float v = acc[mi][ni][r2] * (rd[r2] * wdq) + bv;
        if (GELU) v = 0.5f * v * (1.0f + erff(v * 0.70710678118654752440f));
        C[(size_t)(rowb + r2) * ldc + col] = (CT)v;
      }
    }
  }
}

extern "C" void kernel_launch(void* const* d_in, const int* in_sizes, int n_in,
                              void* d_out, int out_size, void* d_ws, size_t ws_size,
                              hipStream_t stream) {
  (void)in_sizes; (void)n_in; (void)out_size;
  const float* x   = (const float*)d_in[0];
  const float* g1  = (const float*)d_in[1];
  const float* be1 = (const float*)d_in[2];
  const float* w1  = (const float*)d_in[3];
  const float* b1  = (const float*)d_in[4];
  const float* g2  = (const float*)d_in[5];
  const float* be2 = (const float*)d_in[6];
  const float* w2  = (const float*)d_in[7];
  const float* b2  = (const float*)d_in[8];
  float* out = (float*)d_out;

  const int BT = 8 * 4096, D = 1024, H = 4096;
  char* ws = (char*)d_ws;
  float* scales = (float*)(ws);                 // 4 floats
  float* p1     = (float*)(ws + 1024);          // 256 partials (w1)
  float* p2     = (float*)(ws + 2048);          // 256 partials (w2)
  float* rdq1   = (float*)(ws + 4096);          // 32768 fp32
  float* rdq2   = (float*)(ws + 4096 + 131072);
  char* big = ws + (1 << 20);
  bf16* w1q = (bf16*)(big);                     // 8 MB
  bf16* w2q = (bf16*)(big + (8 << 20));         // 8 MB
  bf16* qx1 = (bf16*)(big + (16 << 20));        // 64 MB
  char* h1raw = big + (80 << 20);               // 512 MB (fp32) or 256 MB (bf16)

  const int NW = H * D;  // 4194304 elements per weight
  absmean_partial<<<256, 256, 0, stream>>>(w1, NW, p1);
  absmean_partial<<<256, 256, 0, stream>>>(w2, NW, p2);
  finalize_scales<<<1, 256, 0, stream>>>(p1, p2, 1.0f / NW, 1.0f / NW, scales);
  quant_w<<<NW / 1024, 256, 0, stream>>>(w1, w1q, scales + 0, NW);
  quant_w<<<NW / 1024, 256, 0, stream>>>(w2, w2q, scales + 2, NW);

  ln_quant_kernel<1024, float><<<BT, 256, 0, stream>>>(x, g1, be1, qx1, rdq1, D, D);

  const size_t need_f32 = (size_t)(1 << 20) + (80ull << 20) + (size_t)BT * H * 4;
  if (ws_size >= need_f32) {
    // h1 kept fp32 (matches reference LN2 input precision); LN2 quantizes in-place
    // into each row's first half (bf16, pitch 2H), GEMM2 reads with lda=2H.
    float* h1 = (float*)h1raw;
    gemm_q<true, float><<<(BT / 128) * (H / 128), 256, 0, stream>>>(
        qx1, w1q, h1, rdq1, scales + 1, b1, H, D, D, H);
    ln_quant_kernel<4096, float><<<BT, 256, 0, stream>>>(h1, g2, be2, (bf16*)h1,
                                                         rdq2, H, 2 * H);
    gemm_q<false, float><<<(BT / 128) * (D / 128), 256, 0, stream>>>(
        (bf16*)h1, w2q, out, rdq2, scales + 3, b2, D, H, 2 * H, D);
  } else {
    // fallback: bf16 h1 (337 MB total workspace)
    bf16* h1 = (bf16*)h1raw;
    gemm_q<true, bf16><<<(BT / 128) * (H / 128), 256, 0, stream>>>(
        qx1, w1q, h1, rdq1, scales + 1, b1, H, D, D, H);
    ln_quant_kernel<4096, bf16><<<BT, 256, 0, stream>>>(h1, g2, be2, h1, rdq2, H, H);
    gemm_q<false, float><<<(BT / 128) * (D / 128), 256, 0, stream>>>(
        h1, w2q, out, rdq2, scales + 3, b2, D, H, H, D);
  }
}

// Round 3
// 778.409 us; speedup vs baseline: 1.5247x; 1.5247x over previous
//
#include <hip/hip_runtime.h>
#include <hip/hip_bf16.h>

typedef __bf16 bf16;
typedef __attribute__((ext_vector_type(4))) int intx4;
typedef __attribute__((ext_vector_type(4))) float floatx4;

__device__ __forceinline__ float b2f(unsigned short u) {
  union { unsigned int i; float f; } v; v.i = ((unsigned int)u) << 16; return v.f;
}

__device__ __forceinline__ void async_copy16(const void* g, void* l) {
  __builtin_amdgcn_global_load_lds((__attribute__((address_space(1))) void*)(g),
                                   (__attribute__((address_space(3))) void*)(l),
                                   16, 0, 0);
}

__device__ __forceinline__ float warp_sum(float v) {
  #pragma unroll
  for (int off = 32; off > 0; off >>= 1) v += __shfl_xor(v, off, 64);
  return v;
}
__device__ __forceinline__ float warp_max(float v) {
  #pragma unroll
  for (int off = 32; off > 0; off >>= 1) v = fmaxf(v, __shfl_xor(v, off, 64));
  return v;
}

// exact-erf GELU via A&S 7.1.26 (|eps| <= 1.5e-7), hw rcp + exp
__device__ __forceinline__ float gelu_fast(float v) {
  const float a = fabsf(v) * 0.70710678118654752440f;
  const float t = __builtin_amdgcn_rcpf(fmaf(0.3275911f, a, 1.0f));
  const float e = __expf(-a * a);
  float p = fmaf(1.061405429f, t, -1.453152027f);
  p = fmaf(p, t, 1.421413741f);
  p = fmaf(p, t, -0.284496736f);
  p = fmaf(p, t, 0.254829592f);
  float erfa = fmaf(-p * t, e, 1.0f);          // erf(|v|/sqrt2)
  erfa = copysignf(erfa, v);
  return 0.5f * v * (1.0f + erfa);
}

__device__ __forceinline__ void load4(const float* p, float* v) {
  float4 u = *(const float4*)p;
  v[0] = u.x; v[1] = u.y; v[2] = u.z; v[3] = u.w;
}
__device__ __forceinline__ void load4(const bf16* p, float* v) {
  ushort4 u = *(const ushort4*)p;
  v[0] = b2f(u.x); v[1] = b2f(u.y); v[2] = b2f(u.z); v[3] = b2f(u.w);
}

// ---------------- weight absmean (per-tensor, fp32 input) ----------------
__global__ __launch_bounds__(256) void absmean_partial(const float* __restrict__ w, int n,
                                                       float* __restrict__ partial) {
  const int tid = threadIdx.x;
  const int lane = tid & 63, wave = tid >> 6;
  float s = 0.f;
  for (size_t i = ((size_t)blockIdx.x * 256 + tid) * 4; i < (size_t)n;
       i += (size_t)256 * 256 * 4) {
    float4 u = *(const float4*)(w + i);
    s += fabsf(u.x) + fabsf(u.y) + fabsf(u.z) + fabsf(u.w);
  }
  __shared__ float red[4];
  s = warp_sum(s);
  if (lane == 0) red[wave] = s;
  __syncthreads();
  if (tid == 0) partial[blockIdx.x] = red[0] + red[1] + red[2] + red[3];
}

// scales: [0]=s_w1 (quant), [1]=dq_w1, [2]=s_w2, [3]=dq_w2
__global__ __launch_bounds__(256) void finalize_scales(const float* __restrict__ p1,
                                                       const float* __restrict__ p2,
                                                       float inv_n1, float inv_n2,
                                                       float* __restrict__ scales) {
  const int tid = threadIdx.x;
  const int lane = tid & 63, wave = tid >> 6;
  float a = p1[tid], b = p2[tid];
  a = warp_sum(a); b = warp_sum(b);
  __shared__ float red[8];
  if (lane == 0) { red[wave] = a; red[4 + wave] = b; }
  __syncthreads();
  if (tid == 0) {
    float m1 = fmaxf((red[0] + red[1] + red[2] + red[3]) * inv_n1, 1e-5f);
    float m2 = fmaxf((red[4] + red[5] + red[6] + red[7]) * inv_n2, 1e-5f);
    scales[0] = 1.0f / m1; scales[1] = m1;
    scales[2] = 1.0f / m2; scales[3] = m2;
  }
}

// ternarize fp32 weights -> int8 {-1,0,1}
__global__ __launch_bounds__(256) void quant_w(const float* __restrict__ w,
                                               signed char* __restrict__ wq,
                                               const float* __restrict__ sptr, int n) {
  const int i4 = (blockIdx.x * 256 + threadIdx.x) * 4;
  if (i4 >= n) return;
  const float s = *sptr;
  float4 u = *(const float4*)(w + i4);
  char4 o;
  o.x = (signed char)fminf(fmaxf(rintf(u.x * s), -1.f), 1.f);
  o.y = (signed char)fminf(fmaxf(rintf(u.y * s), -1.f), 1.f);
  o.z = (signed char)fminf(fmaxf(rintf(u.z * s), -1.f), 1.f);
  o.w = (signed char)fminf(fmaxf(rintf(u.w * s), -1.f), 1.f);
  *(char4*)(wq + i4) = o;
}

// ---------------- [gelu] + layernorm + per-row int8 quant ----------------
// one block per row; q may alias x rows (in-place): row fully read into regs
// before first barrier, written after second. px = input pitch (XT elems),
// pq = output pitch (bytes).
template <int D, bool GELU, typename XT>
__global__ __launch_bounds__(256) void ln_quant_kernel(const XT* __restrict__ x,
                                                       const float* __restrict__ gam,
                                                       const float* __restrict__ bet,
                                                       signed char* __restrict__ q,
                                                       float* __restrict__ rdq,
                                                       int px, int pq) {
  constexpr int NC = D / 1024;
  const int tid = threadIdx.x;
  const int lane = tid & 63, wave = tid >> 6;
  const size_t xbase = (size_t)blockIdx.x * px;
  const size_t qbase = (size_t)blockIdx.x * pq;
  float y[NC * 4];
  float s = 0.f, ss = 0.f;
  #pragma unroll
  for (int c = 0; c < NC; ++c) {
    const int idx = (c * 256 + tid) * 4;
    float v[4];
    load4(x + xbase + idx, v);
    #pragma unroll
    for (int j = 0; j < 4; ++j) {
      float vv = GELU ? gelu_fast(v[j]) : v[j];
      y[c * 4 + j] = vv; s += vv; ss += vv * vv;
    }
  }
  __shared__ float red[12];
  float sw = warp_sum(s), qw = warp_sum(ss);
  if (lane == 0) { red[wave] = sw; red[4 + wave] = qw; }
  __syncthreads();
  const float inv_d = 1.0f / (float)D;
  const float mu = (red[0] + red[1] + red[2] + red[3]) * inv_d;
  const float var = (red[4] + red[5] + red[6] + red[7]) * inv_d - mu * mu;
  const float rstd = rsqrtf(var + 1e-5f);
  float amax = 0.f;
  #pragma unroll
  for (int c = 0; c < NC; ++c) {
    const int idx = (c * 256 + tid) * 4;
    float4 gv = *(const float4*)(gam + idx);
    float4 bv = *(const float4*)(bet + idx);
    float gg[4] = {gv.x, gv.y, gv.z, gv.w};
    float bb[4] = {bv.x, bv.y, bv.z, bv.w};
    #pragma unroll
    for (int j = 0; j < 4; ++j) {
      float yy = (y[c * 4 + j] - mu) * rstd * gg[j] + bb[j];
      y[c * 4 + j] = yy;
      amax = fmaxf(amax, fabsf(yy));
    }
  }
  float wm = warp_max(amax);
  if (lane == 0) red[8 + wave] = wm;
  __syncthreads();
  const float am = fmaxf(fmaxf(fmaxf(red[8], red[9]), fmaxf(red[10], red[11])), 1e-5f);
  const float sc = 127.0f / am;
  #pragma unroll
  for (int c = 0; c < NC; ++c) {
    const int idx = (c * 256 + tid) * 4;
    char4 o;
    o.x = (signed char)fminf(fmaxf(rintf(y[c * 4 + 0] * sc), -128.f), 127.f);
    o.y = (signed char)fminf(fmaxf(rintf(y[c * 4 + 1] * sc), -128.f), 127.f);
    o.z = (signed char)fminf(fmaxf(rintf(y[c * 4 + 2] * sc), -128.f), 127.f);
    o.w = (signed char)fminf(fmaxf(rintf(y[c * 4 + 3] * sc), -128.f), 127.f);
    *(char4*)(q + qbase + idx) = o;
  }
  if (tid == 0) rdq[blockIdx.x] = am * (1.0f / 127.0f);
}

// ---------------- int8 GEMM: C[M,N] = A[M,K] * B[N,K]^T ----------------
// mfma_i32_16x16x64_i8; A pitch lda bytes, B pitch KB bytes, C pitch ldc elems.
// 128x128 tile, BK=64 bytes, m97 staging structure (global_load_lds width 16).
template <typename CT>
__global__ __launch_bounds__(256) void gemm_i8(const signed char* __restrict__ A,
                                               const signed char* __restrict__ B,
                                               CT* __restrict__ C,
                                               const float* __restrict__ rdq,
                                               const float* __restrict__ wdq_ptr,
                                               const float* __restrict__ bias,
                                               int N, int KB, int lda, int ldc) {
  __shared__ signed char ldsA[128 * 64];
  __shared__ signed char ldsB[128 * 64];
  const int tid = threadIdx.x;
  const int wave = tid >> 6, lane = tid & 63;
  const int quad = lane >> 4, l16 = lane & 15;
  const int nb = N >> 7;
  const int bm = (int)blockIdx.x / nb;
  const int bn = (int)blockIdx.x % nb;
  const int wm = wave & 1, wn = wave >> 1;

  // 512 16B chunks per tile; chunk = row*4 + colquarter; 2 chunks/thread/operand
  const int ch0 = wave * 128 + lane;
  const int ch1 = ch0 + 64;
  const signed char* a0 = A + (size_t)(bm * 128 + (ch0 >> 2)) * lda + (ch0 & 3) * 16;
  const signed char* a1 = A + (size_t)(bm * 128 + (ch1 >> 2)) * lda + (ch1 & 3) * 16;
  const signed char* b0 = B + (size_t)(bn * 128 + (ch0 >> 2)) * KB + (ch0 & 3) * 16;
  const signed char* b1 = B + (size_t)(bn * 128 + (ch1 >> 2)) * KB + (ch1 & 3) * 16;
  signed char* la0 = &ldsA[(wave * 128) * 16];       // hw adds lane*16
  signed char* la1 = &ldsA[(wave * 128 + 64) * 16];
  signed char* lb0 = &ldsB[(wave * 128) * 16];
  signed char* lb1 = &ldsB[(wave * 128 + 64) * 16];

  intx4 acc[4][4];
  #pragma unroll
  for (int i = 0; i < 4; ++i)
    #pragma unroll
    for (int j = 0; j < 4; ++j) acc[i][j] = (intx4){0, 0, 0, 0};

  const float wdq = *wdq_ptr;

  for (int kb = 0; kb < KB; kb += 64) {
    __syncthreads();
    async_copy16(a0 + kb, la0);
    async_copy16(a1 + kb, la1);
    async_copy16(b0 + kb, lb0);
    async_copy16(b1 + kb, lb1);
    __syncthreads();
    intx4 af[4], bfr[4];
    #pragma unroll
    for (int mi = 0; mi < 4; ++mi) {
      int r = wm * 64 + mi * 16 + l16;
      af[mi] = *(const intx4*)&ldsA[r * 64 + quad * 16];
    }
    #pragma unroll
    for (int ni = 0; ni < 4; ++ni) {
      int r = wn * 64 + ni * 16 + l16;
      bfr[ni] = *(const intx4*)&ldsB[r * 64 + quad * 16];
    }
    #pragma unroll
    for (int mi = 0; mi < 4; ++mi)
      #pragma unroll
      for (int ni = 0; ni < 4; ++ni)
        acc[mi][ni] =
            __builtin_amdgcn_mfma_i32_16x16x64_i8(af[mi], bfr[ni], acc[mi][ni], 0, 0, 0);
  }

  // epilogue: C/D layout col=lane&15, row=quad*4+reg (shape-determined, m121-128)
  #pragma unroll
  for (int mi = 0; mi < 4; ++mi) {
    const int rowb = bm * 128 + wm * 64 + mi * 16 + quad * 4;
    const floatx4 rd = *(const floatx4*)&rdq[rowb];
    #pragma unroll
    for (int ni = 0; ni < 4; ++ni) {
      const int col = bn * 128 + wn * 64 + ni * 16 + l16;
      const float bv = bias[col];
      #pragma unroll
      for (int r2 = 0; r2 < 4; ++r2) {
        float v = fmaf((float)acc[mi][ni][r2], rd[r2] * wdq, bv);
        C[(size_t)(rowb + r2) * ldc + col] = (CT)v;
      }
    }
  }
}

extern "C" void kernel_launch(void* const* d_in, const int* in_sizes, int n_in,
                              void* d_out, int out_size, void* d_ws, size_t ws_size,
                              hipStream_t stream) {
  (void)in_sizes; (void)n_in; (void)out_size; (void)ws_size;
  const float* x   = (const float*)d_in[0];
  const float* g1  = (const float*)d_in[1];
  const float* be1 = (const float*)d_in[2];
  const float* w1  = (const float*)d_in[3];
  const float* b1  = (const float*)d_in[4];
  const float* g2  = (const float*)d_in[5];
  const float* be2 = (const float*)d_in[6];
  const float* w2  = (const float*)d_in[7];
  const float* b2  = (const float*)d_in[8];
  float* out = (float*)d_out;

  const int BT = 8 * 4096, D = 1024, H = 4096;
  char* ws = (char*)d_ws;
  float* scales = (float*)(ws);                 // 4 floats
  float* p1     = (float*)(ws + 1024);
  float* p2     = (float*)(ws + 2048);
  float* rdq1   = (float*)(ws + 4096);          // 32768 fp32
  float* rdq2   = (float*)(ws + 4096 + 131072);
  char* big = ws + (1 << 20);
  signed char* w1q = (signed char*)(big);                 // 4 MB
  signed char* w2q = (signed char*)(big + (4 << 20));     // 4 MB
  signed char* qx1 = (signed char*)(big + (8 << 20));     // 32 MB
  bf16* h1 = (bf16*)(big + (40 << 20));                   // 256 MB -> total ~297 MB

  const int NW = H * D;
  absmean_partial<<<256, 256, 0, stream>>>(w1, NW, p1);
  absmean_partial<<<256, 256, 0, stream>>>(w2, NW, p2);
  finalize_scales<<<1, 256, 0, stream>>>(p1, p2, 1.0f / NW, 1.0f / NW, scales);
  quant_w<<<NW / 1024, 256, 0, stream>>>(w1, w1q, scales + 0, NW);
  quant_w<<<NW / 1024, 256, 0, stream>>>(w2, w2q, scales + 2, NW);

  // LN1 + act quant -> int8
  ln_quant_kernel<1024, false, float><<<BT, 256, 0, stream>>>(x, g1, be1, qx1, rdq1,
                                                              D, D);
  // GEMM1: h1(bf16) = dequant(qx1 . w1q^T) + b1   (pre-GELU; GELU fused into LN2)
  gemm_i8<bf16><<<(BT / 128) * (H / 128), 256, 0, stream>>>(
      qx1, w1q, h1, rdq1, scales + 1, b1, H, D, D, H);
  // GELU + LN2 + act quant, int8 written in-place into h1 row starts (pitch 8192 B)
  ln_quant_kernel<4096, true, bf16><<<BT, 256, 0, stream>>>(
      h1, g2, be2, (signed char*)h1, rdq2, H, 2 * H);
  // GEMM2: out(fp32) = dequant(q . w2q^T) + b2
  gemm_i8<float><<<(BT / 128) * (D / 128), 256, 0, stream>>>(
      (signed char*)h1, w2q, out, rdq2, scales + 3, b2, D, H, 2 * H, D);
}